// Round 1
// 310.890 us; speedup vs baseline: 1.2466x; 1.2466x over previous
//
#include <hip/hip_runtime.h>
#include <hip/hip_bf16.h>

#define Bb 4
#define Nn 1024
#define Dd 512
#define Hh 8
#define Ee 5
#define HDd 64

typedef unsigned int u32_t;
typedef unsigned short u16_t;
typedef short s16x8 __attribute__((ext_vector_type(8)));
typedef float f32x4 __attribute__((ext_vector_type(4)));

#define MFMA(a, b, c) __builtin_amdgcn_mfma_f32_16x16x32_bf16((a), (b), (c), 0, 0, 0)

// pack fp32 -> u32: hi16 = truncated top bf16 bits, lo16 = RN bf16 of remainder.
// value ~= hi + lo with relative error ~2^-17.
__device__ __forceinline__ u32_t pack32(float x) {
    u32_t u = __float_as_uint(x);
    u32_t hi = u & 0xffff0000u;
    float rem = x - __uint_as_float(hi);
    u32_t r = __float_as_uint(rem);
    u32_t lo = (r + 0x7fffu + ((r >> 16) & 1u)) >> 16;
    return hi | (lo & 0xffffu);
}

// 8 packed u32 (as two uint4) -> hi-frag, lo-frag (bf16x8 as short8)
__device__ __forceinline__ void unpk8(uint4 A, uint4 B, s16x8& h, s16x8& l) {
    union { u16_t u[8]; s16x8 v; } H, L;
    u32_t a[8] = {A.x, A.y, A.z, A.w, B.x, B.y, B.z, B.w};
    #pragma unroll
    for (int i = 0; i < 8; i++) { H.u[i] = (u16_t)(a[i] >> 16); L.u[i] = (u16_t)(a[i] & 0xffffu); }
    h = H.v; l = L.v;
}

// split two packed u32 pairs (4 values) into hi-pair/lo-pair u32 words (2 bf16 each)
__device__ __forceinline__ void split4(uint4 A, uint2& hi, uint2& lo) {
    hi.x = (A.x >> 16) | (A.y & 0xffff0000u);
    hi.y = (A.z >> 16) | (A.w & 0xffff0000u);
    lo.x = (A.x & 0xffffu) | (A.y << 16);
    lo.y = (A.z & 0xffffu) | (A.w << 16);
}

// ---------- Kernel 0: normalize node_mask (int32 or byte-bool) -> mw[4096], anyB[4] ----------
__global__ __launch_bounds__(256) void prep_mask(const void* __restrict__ msk,
                                                 int* __restrict__ mw,
                                                 int* __restrict__ anyB) {
    __shared__ int notint;
    __shared__ int ab[Bb];
    const int tid = threadIdx.x;
    if (tid == 0) notint = 0;
    if (tid < Bb) ab[tid] = 0;
    __syncthreads();
    const u32_t* wp = (const u32_t*)msk;
    int bad = 0;
    for (int i = tid; i < 1024; i += 256) bad |= (wp[i] > 1u);
    if (bad) atomicOr(&notint, 1);
    __syncthreads();
    const int isbyte = notint;
    const unsigned char* bp = (const unsigned char*)msk;
    for (int i = tid; i < Bb * Nn; i += 256) {
        const int v = isbyte ? (bp[i] != 0) : (wp[i] != 0);
        mw[i] = v;
        if (v) atomicOr(&ab[i >> 10], 1);
    }
    __syncthreads();
    if (tid < Bb) anyB[tid] = ab[tid];
}

// ---------- Kernel P: one-shot split-bf16 pack of x, w_qkv, w_proj ----------
__global__ __launch_bounds__(256) void pack3(const float* __restrict__ x,
                                             const float* __restrict__ wq,
                                             const float* __restrict__ wpj,
                                             u32_t* __restrict__ xp,
                                             u32_t* __restrict__ wqp,
                                             u32_t* __restrict__ wpp) {
    const int gt = blockIdx.x * 256 + threadIdx.x;
    const int gs = gridDim.x * 256;
    const float4* xs = (const float4*)x;
    uint4* xd = (uint4*)xp;
    for (int i = gt; i < (Bb * Nn * Dd) / 4; i += gs) {
        float4 v = xs[i];
        xd[i] = make_uint4(pack32(v.x), pack32(v.y), pack32(v.z), pack32(v.w));
    }
    const float4* qs = (const float4*)wq;
    uint4* qd = (uint4*)wqp;
    for (int i = gt; i < (3 * Dd * Dd) / 4; i += gs) {
        float4 v = qs[i];
        qd[i] = make_uint4(pack32(v.x), pack32(v.y), pack32(v.z), pack32(v.w));
    }
    const float4* ps = (const float4*)wpj;
    uint4* pd = (uint4*)wpp;
    for (int i = gt; i < (Dd * Dd) / 4; i += gs) {
        float4 v = ps[i];
        pd[i] = make_uint4(pack32(v.x), pack32(v.y), pack32(v.z), pack32(v.w));
    }
}

// ---------- Kernel A: qkv = x @ w_qkv^T via split-bf16 MFMA; inputs pre-packed ----------
__global__ __launch_bounds__(256) void qkv_mfma(const u32_t* __restrict__ xp,
                                                const u32_t* __restrict__ wp,
                                                u32_t* __restrict__ q32,
                                                u32_t* __restrict__ k32,
                                                u32_t* __restrict__ v32) {
    __shared__ __align__(16) u16_t Xh[64 * 72], Xl[64 * 72];
    __shared__ __align__(16) u16_t Wh[64 * 72], Wl[64 * 72];
    const int tid = threadIdx.x;
    const int wv = tid >> 6, lane = tid & 63, lm = lane & 15, quad = lane >> 4;
    const int m0 = blockIdx.y * 64, c0 = blockIdx.x * 64;
    const int row = tid >> 2, dq = tid & 3;
    const uint4* x4 = (const uint4*)xp;
    const uint4* w4 = (const uint4*)wp;

    f32x4 acc[4];
    #pragma unroll
    for (int nt = 0; nt < 4; nt++) acc[nt] = {0.f, 0.f, 0.f, 0.f};

    for (int kt = 0; kt < 8; kt++) {
        __syncthreads();
        #pragma unroll
        for (int t = 0; t < 4; t++) {
            const int cc = dq * 4 + t;                    // uint4-chunk within 64-k slab
            uint4 A = x4[(size_t)(m0 + row) * 128 + kt * 16 + cc];
            uint2 hi, lo;
            split4(A, hi, lo);
            *(uint2*)&Xh[row * 72 + cc * 4] = hi;
            *(uint2*)&Xl[row * 72 + cc * 4] = lo;
            uint4 Bv = w4[(size_t)(c0 + row) * 128 + kt * 16 + cc];
            split4(Bv, hi, lo);
            *(uint2*)&Wh[row * 72 + cc * 4] = hi;
            *(uint2*)&Wl[row * 72 + cc * 4] = lo;
        }
        __syncthreads();
        s16x8 ah[2], al[2];
        #pragma unroll
        for (int ks = 0; ks < 2; ks++) {
            ah[ks] = *(const s16x8*)&Xh[(16 * wv + lm) * 72 + ks * 32 + quad * 8];
            al[ks] = *(const s16x8*)&Xl[(16 * wv + lm) * 72 + ks * 32 + quad * 8];
        }
        #pragma unroll
        for (int nt = 0; nt < 4; nt++) {
            #pragma unroll
            for (int ks = 0; ks < 2; ks++) {
                s16x8 bh = *(const s16x8*)&Wh[(16 * nt + lm) * 72 + ks * 32 + quad * 8];
                s16x8 bl = *(const s16x8*)&Wl[(16 * nt + lm) * 72 + ks * 32 + quad * 8];
                acc[nt] = MFMA(ah[ks], bh, acc[nt]);
                acc[nt] = MFMA(ah[ks], bl, acc[nt]);
                acc[nt] = MFMA(al[ks], bh, acc[nt]);
            }
        }
    }
    #pragma unroll
    for (int nt = 0; nt < 4; nt++) {
        const int c = c0 + 16 * nt + lm;
        const int s = c >> 9, hd = c & 511, h = hd >> 6, d = hd & 63;
        u32_t* dst = (s == 0) ? q32 : (s == 1) ? k32 : v32;
        #pragma unroll
        for (int r = 0; r < 4; r++) {
            const int m = m0 + 16 * wv + 4 * quad + r;
            const int b = m >> 10, n = m & (Nn - 1);
            dst[(((size_t)b * Hh + h) * Nn + n) * HDd + d] = pack32(acc[nt][r]);
        }
    }
}

// ---------- Kernel B: flash attention, split-bf16 MFMA. Block = (i-tile 64, h, b) ----------
// ef loads are unconditional register prefetches issued at iteration top (before K/V
// staging); the pre-MFMA barrier's vmcnt(0) drains them for free. Masking = branchless
// selects. Output written pre-packed (split-bf16 u32) for out_mfma.
__global__ __launch_bounds__(256, 2) void attn_mfma(const u32_t* __restrict__ q32,
                                                    const u32_t* __restrict__ k32,
                                                    const u32_t* __restrict__ v32,
                                                    const float* __restrict__ ef,
                                                    const int* __restrict__ mw,
                                                    const int* __restrict__ anyB,
                                                    const float* __restrict__ wep,
                                                    const float* __restrict__ weg,
                                                    const float* __restrict__ beg,
                                                    u32_t* __restrict__ aoutp) {
    // LDS: Q 18432 + (K alias P) 18432 + VT 22528 = 59392 B -> 2 blocks/CU
    __shared__ __align__(16) u16_t Qh[64 * 72], Ql[64 * 72];
    __shared__ __align__(16) char KP[18432];               // Kh,Kl; later aliased by Ppk
    __shared__ __align__(16) u16_t VTh[64 * 88], VTl[64 * 88];
    u16_t* Kh = (u16_t*)KP;
    u16_t* Kl = Kh + 64 * 72;
    u32_t* Ppk = (u32_t*)KP;                               // 64 x 68 u32 = 17408 B

    const int tid = threadIdx.x;
    const int wv = tid >> 6, lane = tid & 63, lm = lane & 15, quad = lane >> 4;
    const int i0 = blockIdx.x * 64;
    const int h  = blockIdx.y;
    const int b  = blockIdx.z;

    const float wp0 = wep[h*Ee+0], wp1 = wep[h*Ee+1], wp2 = wep[h*Ee+2],
                wp3 = wep[h*Ee+3], wp4 = wep[h*Ee+4];
    const float wg0 = weg[h*Ee+0], wg1 = weg[h*Ee+1], wg2 = weg[h*Ee+2],
                wg3 = weg[h*Ee+3], wg4 = weg[h*Ee+4];
    const float bgs = beg[h];

    const uint4* qg4 = (const uint4*)(q32 + (((size_t)b * Hh + h) * Nn + i0) * HDd);
    const uint4* kg4 = (const uint4*)(k32 + (((size_t)b * Hh + h) * Nn) * HDd);
    const uint4* vg4 = (const uint4*)(v32 + (((size_t)b * Hh + h) * Nn) * HDd);
    const int* mwB = mw + b * Nn;

    // ---- Q staging (once): rows = i-local ----
    {
        const int row = tid >> 2, dq = tid & 3;
        #pragma unroll
        for (int t = 0; t < 4; t++) {
            const int cc = dq * 4 + t;
            uint4 A = qg4[row * 16 + cc];
            uint2 hi, lo;
            split4(A, hi, lo);
            *(uint2*)&Qh[row * 72 + cc * 4] = hi;
            *(uint2*)&Ql[row * 72 + cc * 4] = lo;
        }
    }

    const int anyb = anyB[b];
    int rv[4];
    float m_[4], l_[4];
    f32x4 accO[4];
    const float* efrow[4];
    #pragma unroll
    for (int r = 0; r < 4; r++) {
        const int i = i0 + 16 * wv + 4 * quad + r;
        rv[r] = anyb && mwB[i];
        m_[r] = -1e30f; l_[r] = 0.f;
        efrow[r] = ef + ((size_t)(b * Nn + i) * Nn + lm) * Ee;
    }
    #pragma unroll
    for (int dn = 0; dn < 4; dn++) accO[dn] = {0.f, 0.f, 0.f, 0.f};

    for (int jt = 0; jt < Nn / 64; jt++) {
        const int j0 = jt * 64;

        // ---- unconditional ef/mask prefetch for THIS tile: issued before staging,
        //      drained by the pre-MFMA barrier, consumed in the softmax phase ----
        int mj[4];
        #pragma unroll
        for (int jn = 0; jn < 4; jn++) mj[jn] = mwB[j0 + 16 * jn + lm];
        float er[4][4][5];
        #pragma unroll
        for (int r = 0; r < 4; r++) {
            const float* pr = efrow[r] + (size_t)j0 * Ee;
            #pragma unroll
            for (int jn = 0; jn < 4; jn++) {
                #pragma unroll
                for (int e = 0; e < 5; e++) er[r][jn][e] = pr[jn * (16 * Ee) + e];
            }
        }

        __syncthreads();   // prev-tile frag reads done (also covers Q staging on jt=0)

        // ---- K stage: [j][d] split ----
        {
            const int row = tid >> 2, dq = tid & 3;
            #pragma unroll
            for (int t = 0; t < 4; t++) {
                const int cc = dq * 4 + t;
                uint4 A = kg4[(j0 + row) * 16 + cc];
                uint2 hi, lo;
                split4(A, hi, lo);
                *(uint2*)&Kh[row * 72 + cc * 4] = hi;
                *(uint2*)&Kl[row * 72 + cc * 4] = lo;
            }
        }
        // ---- V stage transposed: VT[d][j] split ----
        {
            const int jg = tid >> 4, dc = tid & 15;
            u32_t r0[4], r1[4], r2[4], r3[4];
            uint4 A0 = vg4[(j0 + 4 * jg + 0) * 16 + dc];
            uint4 A1 = vg4[(j0 + 4 * jg + 1) * 16 + dc];
            uint4 A2 = vg4[(j0 + 4 * jg + 2) * 16 + dc];
            uint4 A3 = vg4[(j0 + 4 * jg + 3) * 16 + dc];
            r0[0]=A0.x; r0[1]=A0.y; r0[2]=A0.z; r0[3]=A0.w;
            r1[0]=A1.x; r1[1]=A1.y; r1[2]=A1.z; r1[3]=A1.w;
            r2[0]=A2.x; r2[1]=A2.y; r2[2]=A2.z; r2[3]=A2.w;
            r3[0]=A3.x; r3[1]=A3.y; r3[2]=A3.z; r3[3]=A3.w;
            #pragma unroll
            for (int c = 0; c < 4; c++) {
                const int d = 4 * dc + c;
                uint2 hi, lo;
                hi.x = (r0[c] >> 16) | (r1[c] & 0xffff0000u);
                hi.y = (r2[c] >> 16) | (r3[c] & 0xffff0000u);
                lo.x = (r0[c] & 0xffffu) | (r1[c] << 16);
                lo.y = (r2[c] & 0xffffu) | (r3[c] << 16);
                *(uint2*)&VTh[d * 88 + 4 * jg] = hi;
                *(uint2*)&VTl[d * 88 + 4 * jg] = lo;
            }
        }
        __syncthreads();

        // ---- QK^T: S[16 x 64] per wave ----
        s16x8 qh[2], ql[2];
        #pragma unroll
        for (int ks = 0; ks < 2; ks++) {
            qh[ks] = *(const s16x8*)&Qh[(16 * wv + lm) * 72 + ks * 32 + quad * 8];
            ql[ks] = *(const s16x8*)&Ql[(16 * wv + lm) * 72 + ks * 32 + quad * 8];
        }
        f32x4 S[4];
        #pragma unroll
        for (int jn = 0; jn < 4; jn++) {
            f32x4 s = {0.f, 0.f, 0.f, 0.f};
            #pragma unroll
            for (int ks = 0; ks < 2; ks++) {
                s16x8 bh = *(const s16x8*)&Kh[(16 * jn + lm) * 72 + ks * 32 + quad * 8];
                s16x8 bl = *(const s16x8*)&Kl[(16 * jn + lm) * 72 + ks * 32 + quad * 8];
                s = MFMA(qh[ks], bh, s);
                s = MFMA(qh[ks], bl, s);
                s = MFMA(ql[ks], bh, s);
            }
            S[jn] = s;
        }

        // ---- gate/bias/mask + online softmax (branchless); rows = 16wv+4quad+r ----
        float pv[4][4];
        #pragma unroll
        for (int r = 0; r < 4; r++) {
            float sv[4];
            #pragma unroll
            for (int jn = 0; jn < 4; jn++) {
                const float e0 = er[r][jn][0], e1 = er[r][jn][1], e2 = er[r][jn][2],
                            e3 = er[r][jn][3], e4 = er[r][jn][4];
                const float bias = fmaf(e0, wp0, fmaf(e1, wp1, fmaf(e2, wp2, fmaf(e3, wp3, e4 * wp4))));
                const float gv = fmaf(e0, wg0, fmaf(e1, wg1, fmaf(e2, wg2, fmaf(e3, wg3, fmaf(e4, wg4, bgs)))));
                const float gate = __builtin_amdgcn_rcpf(1.f + __expf(-gv));
                const float val = fmaf(S[jn][r], 0.125f, gate * bias);
                sv[jn] = rv[r] ? (mj[jn] ? val : -1e30f) : 0.f;
            }
            float tmax = fmaxf(fmaxf(sv[0], sv[1]), fmaxf(sv[2], sv[3]));
            tmax = fmaxf(tmax, __shfl_xor(tmax, 1));
            tmax = fmaxf(tmax, __shfl_xor(tmax, 2));
            tmax = fmaxf(tmax, __shfl_xor(tmax, 4));
            tmax = fmaxf(tmax, __shfl_xor(tmax, 8));
            const float mnew = fmaxf(m_[r], tmax);
            const float alpha = __expf(m_[r] - mnew);
            float ps = 0.f;
            #pragma unroll
            for (int jn = 0; jn < 4; jn++) { pv[r][jn] = __expf(sv[jn] - mnew); ps += pv[r][jn]; }
            ps += __shfl_xor(ps, 1);
            ps += __shfl_xor(ps, 2);
            ps += __shfl_xor(ps, 4);
            ps += __shfl_xor(ps, 8);
            m_[r] = mnew;
            l_[r] = l_[r] * alpha + ps;
            #pragma unroll
            for (int dn = 0; dn < 4; dn++) accO[dn][r] *= alpha;
        }

        __syncthreads();   // all waves done with Kh/Kl frags; safe to overwrite with P
        #pragma unroll
        for (int r = 0; r < 4; r++)
            #pragma unroll
            for (int jn = 0; jn < 4; jn++)
                Ppk[(16 * wv + 4 * quad + r) * 68 + 16 * jn + lm] = pack32(pv[r][jn]);

        // ---- PV: reads only this wave's own P rows (16wv..16wv+15) ----
        s16x8 ph[2], pl[2];
        #pragma unroll
        for (int ks2 = 0; ks2 < 2; ks2++) {
            const int off = (16 * wv + lm) * 68 + ks2 * 32 + quad * 8;
            uint4 A = *(const uint4*)&Ppk[off];
            uint4 B = *(const uint4*)&Ppk[off + 4];
            unpk8(A, B, ph[ks2], pl[ks2]);
        }
        #pragma unroll
        for (int dn = 0; dn < 4; dn++) {
            f32x4 c = accO[dn];
            #pragma unroll
            for (int ks2 = 0; ks2 < 2; ks2++) {
                s16x8 vh = *(const s16x8*)&VTh[(16 * dn + lm) * 88 + ks2 * 32 + quad * 8];
                s16x8 vl = *(const s16x8*)&VTl[(16 * dn + lm) * 88 + ks2 * 32 + quad * 8];
                c = MFMA(ph[ks2], vh, c);
                c = MFMA(ph[ks2], vl, c);
                c = MFMA(pl[ks2], vh, c);
            }
            accO[dn] = c;
        }
    }

    #pragma unroll
    for (int r = 0; r < 4; r++) {
        const int i = i0 + 16 * wv + 4 * quad + r;
        const float inv = __builtin_amdgcn_rcpf(l_[r]);
        #pragma unroll
        for (int dn = 0; dn < 4; dn++)
            aoutp[(size_t)(b * Nn + i) * Dd + h * HDd + 16 * dn + lm] = pack32(accO[dn][r] * inv);
    }
}

// ---------- Kernel C: out = aout @ w_proj^T + bias; inputs pre-packed ----------
__global__ __launch_bounds__(256) void out_mfma(const u32_t* __restrict__ ap,
                                                const u32_t* __restrict__ wp,
                                                const float* __restrict__ bias,
                                                float* __restrict__ out) {
    __shared__ __align__(16) u16_t Xh[64 * 72], Xl[64 * 72];
    __shared__ __align__(16) u16_t Wh[64 * 72], Wl[64 * 72];
    const int tid = threadIdx.x;
    const int wv = tid >> 6, lane = tid & 63, lm = lane & 15, quad = lane >> 4;
    const int m0 = blockIdx.y * 64, c0 = blockIdx.x * 64;
    const int row = tid >> 2, dq = tid & 3;
    const uint4* a4 = (const uint4*)ap;
    const uint4* w4 = (const uint4*)wp;

    f32x4 acc[4];
    #pragma unroll
    for (int nt = 0; nt < 4; nt++) acc[nt] = {0.f, 0.f, 0.f, 0.f};

    for (int kt = 0; kt < 8; kt++) {
        __syncthreads();
        #pragma unroll
        for (int t = 0; t < 4; t++) {
            const int cc = dq * 4 + t;
            uint4 A = a4[(size_t)(m0 + row) * 128 + kt * 16 + cc];
            uint2 hi, lo;
            split4(A, hi, lo);
            *(uint2*)&Xh[row * 72 + cc * 4] = hi;
            *(uint2*)&Xl[row * 72 + cc * 4] = lo;
            uint4 Bv = w4[(size_t)(c0 + row) * 128 + kt * 16 + cc];
            split4(Bv, hi, lo);
            *(uint2*)&Wh[row * 72 + cc * 4] = hi;
            *(uint2*)&Wl[row * 72 + cc * 4] = lo;
        }
        __syncthreads();
        s16x8 ah[2], al[2];
        #pragma unroll
        for (int ks = 0; ks < 2; ks++) {
            ah[ks] = *(const s16x8*)&Xh[(16 * wv + lm) * 72 + ks * 32 + quad * 8];
            al[ks] = *(const s16x8*)&Xl[(16 * wv + lm) * 72 + ks * 32 + quad * 8];
        }
        #pragma unroll
        for (int nt = 0; nt < 4; nt++) {
            #pragma unroll
            for (int ks = 0; ks < 2; ks++) {
                s16x8 bh = *(const s16x8*)&Wh[(16 * nt + lm) * 72 + ks * 32 + quad * 8];
                s16x8 bl = *(const s16x8*)&Wl[(16 * nt + lm) * 72 + ks * 32 + quad * 8];
                acc[nt] = MFMA(ah[ks], bh, acc[nt]);
                acc[nt] = MFMA(ah[ks], bl, acc[nt]);
                acc[nt] = MFMA(al[ks], bh, acc[nt]);
            }
        }
    }
    #pragma unroll
    for (int nt = 0; nt < 4; nt++) {
        const int c = c0 + 16 * nt + lm;
        const float bc = bias[c];
        #pragma unroll
        for (int r = 0; r < 4; r++) {
            const int m = m0 + 16 * wv + 4 * quad + r;
            out[(size_t)m * Dd + c] = acc[nt][r] + bc;
        }
    }
}

extern "C" void kernel_launch(void* const* d_in, const int* in_sizes, int n_in,
                              void* d_out, int out_size, void* d_ws, size_t ws_size,
                              hipStream_t stream) {
    const float* x    = (const float*)d_in[0];
    const float* ef   = (const float*)d_in[1];
    const void*  msk  = d_in[2];
    const float* wqkv = (const float*)d_in[3];
    const float* wep  = (const float*)d_in[4];
    const float* weg  = (const float*)d_in[5];
    const float* beg  = (const float*)d_in[6];
    const float* wpj  = (const float*)d_in[7];
    const float* bpj  = (const float*)d_in[8];
    float* out = (float*)d_out;

    int* mw   = (int*)d_ws;                       // 4096 ints
    int* anyB = mw + Bb * Nn;                     // 16 ints
    u32_t* q32 = (u32_t*)(anyB + 16);
    const size_t per = (size_t)Bb * Hh * Nn * HDd;   // 2,097,152
    u32_t* k32 = q32 + per;
    u32_t* v32 = k32 + per;
    u32_t* aop = v32 + per;                       // B*N*D packed u32
    u32_t* xp  = aop + (size_t)Bb * Nn * Dd;      // B*N*D packed u32
    u32_t* wqp = xp + (size_t)Bb * Nn * Dd;       // 3*D*D packed u32
    u32_t* wpp = wqp + (size_t)3 * Dd * Dd;       // D*D packed u32

    prep_mask<<<1, 256, 0, stream>>>(msk, mw, anyB);
    pack3<<<1024, 256, 0, stream>>>(x, wqkv, wpj, xp, wqp, wpp);
    qkv_mfma<<<dim3(24, 64), 256, 0, stream>>>(xp, wqp, q32, k32, v32);
    attn_mfma<<<dim3(Nn / 64, Hh, Bb), 256, 0, stream>>>(q32, k32, v32, ef, mw, anyB,
                                                         wep, weg, beg, aop);
    out_mfma<<<dim3(8, 64), 256, 0, stream>>>(aop, wpp, bpj, out);
}